// Round 26
// baseline (49.887 us; speedup 1.0000x reference)
//
#include <hip/hip_runtime.h>
#include <hip/hip_bf16.h>

#define BATCH 8
#define NPTS  8192
#define NPT_TOT (BATCH * NPTS)   // 65536 points per cloud

typedef __attribute__((ext_vector_type(8)))  short short8;
typedef __attribute__((ext_vector_type(16))) float float16;
typedef unsigned int uint32;

// order-preserving float->uint map for atomicMax
__device__ __forceinline__ uint32 map_f(float f) {
    int i = __float_as_int(f);
    return (uint32)(i ^ ((i >> 31) | 0x80000000));
}
__device__ __forceinline__ float unmap_f(uint32 u) {
    int i = (u & 0x80000000u) ? (int)(u ^ 0x80000000u) : (int)~u;
    return __int_as_float(i);
}

__device__ __forceinline__ unsigned short bf16_of(float f) {
    __hip_bfloat16 h = __float2bfloat16(f);
    return *reinterpret_cast<unsigned short*>(&h);
}
__device__ __forceinline__ float f_of_bf16(unsigned short u) {
    __hip_bfloat16 h = *reinterpret_cast<__hip_bfloat16*>(&u);
    return __bfloat162float(h);
}
__device__ __forceinline__ uint32 pk(unsigned short lo, unsigned short hi) {
    return (uint32)lo | ((uint32)hi << 16);
}
// single-instruction 3-input max
__device__ __forceinline__ float max3f(float a, float b, float c) {
    float d;
    asm("v_max3_f32 %0, %1, %2, %3" : "=v"(d) : "v"(a), "v"(b), "v"(c));
    return d;
}

// ---------------------------------------------------------------------------
// prepass: per point build K-major 16-slot bf16 hi/lo vectors (identical to
// the passing r16/r21/r24 prepass) + zero-init smax.
// ---------------------------------------------------------------------------
__global__ __launch_bounds__(256)
void prepass(const float* __restrict__ gts, const float* __restrict__ preds,
             float* __restrict__ norms, uint32* __restrict__ smax,
             unsigned short* __restrict__ AG, unsigned short* __restrict__ BG,
             unsigned short* __restrict__ AP, unsigned short* __restrict__ BP)
{
    int i = blockIdx.x * blockDim.x + threadIdx.x;
    if (i >= 2 * NPT_TOT) return;
    const bool isGt = i < NPT_TOT;
    const int j = isGt ? i : i - NPT_TOT;
    const float* src = (isGt ? gts : preds) + 3 * (size_t)j;
    const float x = src[0], y = src[1], z = src[2];
    const float h = 0.5f * (x * x + y * y + z * z);
    norms[i] = h;       // [haa | hbb]
    smax[i]  = 0u;      // mapped: below every real value

    const unsigned short xh = bf16_of(x), yh = bf16_of(y), zh = bf16_of(z);
    const unsigned short xl = bf16_of(x - f_of_bf16(xh));
    const unsigned short yl = bf16_of(y - f_of_bf16(yh));
    const unsigned short zl = bf16_of(z - f_of_bf16(zh));
    const unsigned short nhh = bf16_of(-h);
    const unsigned short nhl = bf16_of(-h - f_of_bf16(nhh));
    const unsigned short one = 0x3F80;

    // A: point-major
    unsigned short* A = (isGt ? AG : AP) + (size_t)j * 16;
    uint4 av0 = { pk(xh, yh), pk(zh, xl), pk(yl, zl), pk(xh, yh) };
    uint4 av1 = { pk(zh, xl), pk(yl, zl), pk(one, one), 0u };
    *reinterpret_cast<uint4*>(A)     = av0;
    *reinterpret_cast<uint4*>(A + 8) = av1;

    // B: tile-major fragments
    const int b = j >> 13;          // batch
    const int q = j & 8191;         // point within batch
    const int t = q >> 5, p = q & 31;
    unsigned short* Bf = (isGt ? BG : BP) + ((size_t)b * 16384 + t * 64 + p) * 8;
    uint4 bv0 = { pk(xh, yh), pk(zh, xh), pk(yh, zh), pk(xl, yl) };   // K-half 0
    uint4 bv1 = { pk(zl, xl), pk(yl, zl), pk(nhh, nhl), 0u };         // K-half 1
    *reinterpret_cast<uint4*>(Bf)            = bv0;
    *reinterpret_cast<uint4*>(Bf + 32 * 8)   = bv1;
}

// ---------------------------------------------------------------------------
// main: byte-identical to the passing r25 kernel EXCEPT the tile-visit order:
// each wave starts its sweep at tile wid*8 (mod 32). Column-max is order-
// invariant, so results are identical; the only change is CROSS-WAVE PHASE —
// the 4 waves' MFMA bursts now occupy disjoint phase slots instead of
// colliding in lockstep after __syncthreads (the one cross-wave property
// every r14-r25 variant shared; r11's VALUBusy=97% proves interleave works
// when the streams aren't phase-locked).
// ---------------------------------------------------------------------------
#define MFMA4_V(D0, D1, D2, D3, BV, A0, A1, A2, A3, Z)                       \
    asm volatile("v_mfma_f32_32x32x16_bf16 %0, %4, %5, %9\n\t"               \
                 "v_mfma_f32_32x32x16_bf16 %1, %4, %6, %9\n\t"               \
                 "v_mfma_f32_32x32x16_bf16 %2, %4, %7, %9\n\t"               \
                 "v_mfma_f32_32x32x16_bf16 %3, %4, %8, %9\n\t"               \
                 "s_nop 7\n\t"                                               \
                 "s_nop 7"                                                   \
                 : "=&v"(D0), "=&v"(D1), "=&v"(D2), "=&v"(D3)                \
                 : "v"(BV), "v"(A0), "v"(A1), "v"(A2), "v"(A3), "v"(Z))

#define RED8(d, mx)                                   \
    {  mx = max3f(d[0],  d[1],  mx);                  \
       mx = max3f(d[2],  d[3],  mx);                  \
       mx = max3f(d[4],  d[5],  mx);                  \
       mx = max3f(d[6],  d[7],  mx);                  \
       mx = max3f(d[8],  d[9],  mx);                  \
       mx = max3f(d[10], d[11], mx);                  \
       mx = max3f(d[12], d[13], mx);                  \
       mx = max3f(d[14], d[15], mx); }

#define CT 32   // col-tiles per block (1024 cols); 8 chunks cover 8192 cols

__global__ __launch_bounds__(256, 4)
void chamfer_mfma(const unsigned short* __restrict__ AG,
                  const unsigned short* __restrict__ BP,
                  const unsigned short* __restrict__ AP,
                  const unsigned short* __restrict__ BG,
                  uint32* __restrict__ smax_all)
{
    __shared__ short8 sb[CT * 64];           // 32 KB col-chunk

    const int tid   = threadIdx.x;
    const int lane  = tid & 63;
    const int wid   = tid >> 6;
    const int dir   = blockIdx.z >> 3;       // 0: gts-rows, 1: preds-rows
    const int batch = blockIdx.z & 7;
    const int row0  = blockIdx.y * 512 + wid * 128;

    const unsigned short* Arows = dir ? AP : AG;
    const unsigned short* Bcols = dir ? BG : BP;
    uint32* smax = smax_all + dir * NPT_TOT;

    const int lr = lane & 31, lg = lane >> 5;

    // stage the block's 32-tile col-chunk (coalesced, 8 x 16B per thread)
    const short8* gB = reinterpret_cast<const short8*>(Bcols)
                     + (size_t)batch * 16384 + (size_t)blockIdx.x * (CT * 64);
#pragma unroll
    for (int s = 0; s < 8; ++s) sb[s * 256 + tid] = gB[s * 256 + tid];

    // row-points as MFMA B-operand fragments (point-major A array)
    const short8* gA = reinterpret_cast<const short8*>(Arows);
    const size_t abase = ((size_t)batch * NPTS + row0 + lr) * 2 + lg;
    const short8 a0 = gA[abase];
    const short8 a1 = gA[abase + 64];    // +32 rows
    const short8 a2 = gA[abase + 128];   // +64 rows
    const short8 a3 = gA[abase + 192];   // +96 rows

    // zero C held in VGPRs; MFMA D tuples are distinct -> stays zero forever
    float16 z16 = {0.f, 0.f, 0.f, 0.f, 0.f, 0.f, 0.f, 0.f,
                   0.f, 0.f, 0.f, 0.f, 0.f, 0.f, 0.f, 0.f};
    float mx0 = -INFINITY, mx1 = -INFINITY, mx2 = -INFINITY, mx3 = -INFINITY;

    __syncthreads();

    const int phase = wid * 8;               // de-phase the 4 waves
    for (int it = 0; it < CT; it += 2) {
        const int tt = (it + phase) & (CT - 1);   // even, so tt+1 <= CT-1
        const short8 bv0 = sb[tt * 64 + lane];
        const short8 bv1 = sb[(tt + 1) * 64 + lane];

        float16 d0, d1, d2, d3;
        MFMA4_V(d0, d1, d2, d3, bv0, a0, a1, a2, a3, z16);
        RED8(d0, mx0);
        RED8(d1, mx1);
        RED8(d2, mx2);
        RED8(d3, mx3);

        // d-buffer reuse: MFMA writes happen strictly after the max3 reads
        // above (in-order issue, later completion) — safe.
        MFMA4_V(d0, d1, d2, d3, bv1, a0, a1, a2, a3, z16);
        RED8(d0, mx0);
        RED8(d1, mx1);
        RED8(d2, mx2);
        RED8(d3, mx3);
    }

    // lanes l and l+32 hold maxes over disjoint col subsets for the same row
    mx0 = fmaxf(mx0, __shfl_xor(mx0, 32, 64));
    mx1 = fmaxf(mx1, __shfl_xor(mx1, 32, 64));
    mx2 = fmaxf(mx2, __shfl_xor(mx2, 32, 64));
    mx3 = fmaxf(mx3, __shfl_xor(mx3, 32, 64));
    if (lane < 32) {
        uint32* s = smax + batch * NPTS + row0 + lane;
        atomicMax(s,      map_f(mx0));
        atomicMax(s + 32, map_f(mx1));
        atomicMax(s + 64, map_f(mx2));
        atomicMax(s + 96, map_f(mx3));
    }
}

// ---------------------------------------------------------------------------
// deterministic 2-stage final sum: loss = 2 * sum_i (norms[i] - unmap(smax[i]))
// ---------------------------------------------------------------------------
__global__ __launch_bounds__(256)
void final_stage1(const float* __restrict__ norms, const uint32* __restrict__ smax,
                  float* __restrict__ partials)
{
    const int base = blockIdx.x * 1024;
    float s = 0.f;
    for (int k = threadIdx.x; k < 1024; k += 256) {
        const int i = base + k;
        s += norms[i] - unmap_f(smax[i]);
    }
#pragma unroll
    for (int off = 32; off; off >>= 1) s += __shfl_down(s, off, 64);
    __shared__ float ws4[4];
    if ((threadIdx.x & 63) == 0) ws4[threadIdx.x >> 6] = s;
    __syncthreads();
    if (threadIdx.x == 0) partials[blockIdx.x] = (ws4[0] + ws4[1]) + (ws4[2] + ws4[3]);
}

__global__ void final_stage2(const float* __restrict__ partials, float* __restrict__ out)
{
    float s = partials[threadIdx.x] + partials[threadIdx.x + 64];
#pragma unroll
    for (int off = 32; off; off >>= 1) s += __shfl_down(s, off, 64);
    if (threadIdx.x == 0) *out = 2.0f * s;
}

extern "C" void kernel_launch(void* const* d_in, const int* in_sizes, int n_in,
                              void* d_out, int out_size, void* d_ws, size_t ws_size,
                              hipStream_t stream) {
    const float* preds = (const float*)d_in[0];  // [B, M, 3]
    const float* gts   = (const float*)d_in[1];  // [B, N, 3]

    char* w = (char*)d_ws;
    float*  norms = (float*)w;                                   // 512 KiB  [haa|hbb]
    uint32* smax  = (uint32*)(w + 8 * (size_t)NPT_TOT);          // 512 KiB  [smax1|smax2]
    const size_t PITCH = 32 * (size_t)NPT_TOT;                   // 2 MiB per packed array
    unsigned short* AG = (unsigned short*)(w + 16 * (size_t)NPT_TOT);
    unsigned short* BG = (unsigned short*)((char*)AG + PITCH);
    unsigned short* AP = (unsigned short*)((char*)AG + 2 * PITCH);
    unsigned short* BP = (unsigned short*)((char*)AG + 3 * PITCH);
    float* partials = (float*)((char*)AG + 4 * PITCH);

    prepass<<<(2 * NPT_TOT) / 256, 256, 0, stream>>>(gts, preds, norms, smax,
                                                     AG, BG, AP, BP);

    // both directions in one launch: z = dir*8 + batch; 1024-col chunks
    dim3 grid(8, 16, 16);   // 2048 blocks
    chamfer_mfma<<<grid, 256, 0, stream>>>(AG, BP, AP, BG, smax);

    final_stage1<<<128, 256, 0, stream>>>(norms, smax, partials);
    final_stage2<<<1, 64, 0, stream>>>(partials, (float*)d_out);
}

// Round 28
// 49.701 us; speedup vs baseline: 1.0037x; 1.0037x over previous
//
#include <hip/hip_runtime.h>
#include <hip/hip_bf16.h>

#define BATCH 8
#define NPTS  8192
#define NPT_TOT (BATCH * NPTS)   // 65536 points per cloud

typedef __attribute__((ext_vector_type(8)))  short short8;
typedef __attribute__((ext_vector_type(16))) float float16;
typedef unsigned int uint32;

// order-preserving float->uint map for atomicMax
__device__ __forceinline__ uint32 map_f(float f) {
    int i = __float_as_int(f);
    return (uint32)(i ^ ((i >> 31) | 0x80000000));
}
__device__ __forceinline__ float unmap_f(uint32 u) {
    int i = (u & 0x80000000u) ? (int)(u ^ 0x80000000u) : (int)~u;
    return __int_as_float(i);
}

__device__ __forceinline__ unsigned short bf16_of(float f) {
    __hip_bfloat16 h = __float2bfloat16(f);
    return *reinterpret_cast<unsigned short*>(&h);
}
__device__ __forceinline__ float f_of_bf16(unsigned short u) {
    __hip_bfloat16 h = *reinterpret_cast<__hip_bfloat16*>(&u);
    return __bfloat162float(h);
}
__device__ __forceinline__ uint32 pk(unsigned short lo, unsigned short hi) {
    return (uint32)lo | ((uint32)hi << 16);
}
// single-instruction 3-input max
__device__ __forceinline__ float max3f(float a, float b, float c) {
    float d;
    asm("v_max3_f32 %0, %1, %2, %3" : "=v"(d) : "v"(a), "v"(b), "v"(c));
    return d;
}

// ---------------------------------------------------------------------------
// prepass: per point build K-major 16-slot bf16 hi/lo vectors.
//   Row-form (A), point-major [pt][16]:  [xh yh zh | xl yl zl | xh yh zh | xl yl zl | 1 1 0 0]
//   Col-form (B), TILE-major:            [xh yh zh | xh yh zh | xl yl zl | xl yl zl | -hh -hl 0 0]
// sum_k Row[k](a)*Col[k](b) = (ah+al).(bh+bl) - 0.5|b|^2
// ---------------------------------------------------------------------------
__global__ __launch_bounds__(256)
void prepass(const float* __restrict__ gts, const float* __restrict__ preds,
             float* __restrict__ norms, uint32* __restrict__ smax,
             unsigned short* __restrict__ AG, unsigned short* __restrict__ BG,
             unsigned short* __restrict__ AP, unsigned short* __restrict__ BP)
{
    int i = blockIdx.x * blockDim.x + threadIdx.x;
    if (i >= 2 * NPT_TOT) return;
    const bool isGt = i < NPT_TOT;
    const int j = isGt ? i : i - NPT_TOT;
    const float* src = (isGt ? gts : preds) + 3 * (size_t)j;
    const float x = src[0], y = src[1], z = src[2];
    const float h = 0.5f * (x * x + y * y + z * z);
    norms[i] = h;       // [haa | hbb]
    smax[i]  = 0u;      // mapped: below every real value

    const unsigned short xh = bf16_of(x), yh = bf16_of(y), zh = bf16_of(z);
    const unsigned short xl = bf16_of(x - f_of_bf16(xh));
    const unsigned short yl = bf16_of(y - f_of_bf16(yh));
    const unsigned short zl = bf16_of(z - f_of_bf16(zh));
    const unsigned short nhh = bf16_of(-h);
    const unsigned short nhl = bf16_of(-h - f_of_bf16(nhh));
    const unsigned short one = 0x3F80;

    // A: point-major
    unsigned short* A = (isGt ? AG : AP) + (size_t)j * 16;
    uint4 av0 = { pk(xh, yh), pk(zh, xl), pk(yl, zl), pk(xh, yh) };
    uint4 av1 = { pk(zh, xl), pk(yl, zl), pk(one, one), 0u };
    *reinterpret_cast<uint4*>(A)     = av0;
    *reinterpret_cast<uint4*>(A + 8) = av1;

    // B: tile-major fragments
    const int b = j >> 13;          // batch
    const int q = j & 8191;         // point within batch
    const int t = q >> 5, p = q & 31;
    unsigned short* Bf = (isGt ? BG : BP) + ((size_t)b * 16384 + t * 64 + p) * 8;
    uint4 bv0 = { pk(xh, yh), pk(zh, xh), pk(yh, zh), pk(xl, yl) };   // K-half 0
    uint4 bv1 = { pk(zl, xl), pk(yl, zl), pk(nhh, nhl), 0u };         // K-half 1
    *reinterpret_cast<uint4*>(Bf)            = bv0;
    *reinterpret_cast<uint4*>(Bf + 32 * 8)   = bv1;
}

// ---------------------------------------------------------------------------
// main (final form, = passing r25): both directions in one launch, CT=32
// (32 KB LDS chunk, 2048 blocks), 4 row-tiles/wave, single-blob 4-MFMA asm
// groups with internal s_nop hazard fences, v_max3 reduce, atomicMax epilogue.
// ---------------------------------------------------------------------------
#define MFMA4_V(D0, D1, D2, D3, BV, A0, A1, A2, A3, Z)                       \
    asm volatile("v_mfma_f32_32x32x16_bf16 %0, %4, %5, %9\n\t"               \
                 "v_mfma_f32_32x32x16_bf16 %1, %4, %6, %9\n\t"               \
                 "v_mfma_f32_32x32x16_bf16 %2, %4, %7, %9\n\t"               \
                 "v_mfma_f32_32x32x16_bf16 %3, %4, %8, %9\n\t"               \
                 "s_nop 7\n\t"                                               \
                 "s_nop 7"                                                   \
                 : "=&v"(D0), "=&v"(D1), "=&v"(D2), "=&v"(D3)                \
                 : "v"(BV), "v"(A0), "v"(A1), "v"(A2), "v"(A3), "v"(Z))

#define RED8(d, mx)                                   \
    {  mx = max3f(d[0],  d[1],  mx);                  \
       mx = max3f(d[2],  d[3],  mx);                  \
       mx = max3f(d[4],  d[5],  mx);                  \
       mx = max3f(d[6],  d[7],  mx);                  \
       mx = max3f(d[8],  d[9],  mx);                  \
       mx = max3f(d[10], d[11], mx);                  \
       mx = max3f(d[12], d[13], mx);                  \
       mx = max3f(d[14], d[15], mx); }

#define CT 32   // col-tiles per block (1024 cols); 8 chunks cover 8192 cols

__global__ __launch_bounds__(256, 4)
void chamfer_mfma(const unsigned short* __restrict__ AG,
                  const unsigned short* __restrict__ BP,
                  const unsigned short* __restrict__ AP,
                  const unsigned short* __restrict__ BG,
                  uint32* __restrict__ smax_all)
{
    __shared__ short8 sb[CT * 64];           // 32 KB col-chunk

    const int tid   = threadIdx.x;
    const int lane  = tid & 63;
    const int wid   = tid >> 6;
    const int dir   = blockIdx.z >> 3;       // 0: gts-rows, 1: preds-rows
    const int batch = blockIdx.z & 7;
    const int row0  = blockIdx.y * 512 + wid * 128;

    const unsigned short* Arows = dir ? AP : AG;
    const unsigned short* Bcols = dir ? BG : BP;
    uint32* smax = smax_all + dir * NPT_TOT;

    const int lr = lane & 31, lg = lane >> 5;

    // stage the block's 32-tile col-chunk (coalesced, 8 x 16B per thread)
    const short8* gB = reinterpret_cast<const short8*>(Bcols)
                     + (size_t)batch * 16384 + (size_t)blockIdx.x * (CT * 64);
#pragma unroll
    for (int s = 0; s < 8; ++s) sb[s * 256 + tid] = gB[s * 256 + tid];

    // row-points as MFMA B-operand fragments (point-major A array)
    const short8* gA = reinterpret_cast<const short8*>(Arows);
    const size_t abase = ((size_t)batch * NPTS + row0 + lr) * 2 + lg;
    const short8 a0 = gA[abase];
    const short8 a1 = gA[abase + 64];    // +32 rows
    const short8 a2 = gA[abase + 128];   // +64 rows
    const short8 a3 = gA[abase + 192];   // +96 rows

    // zero C held in VGPRs; MFMA D tuples are distinct -> stays zero forever
    float16 z16 = {0.f, 0.f, 0.f, 0.f, 0.f, 0.f, 0.f, 0.f,
                   0.f, 0.f, 0.f, 0.f, 0.f, 0.f, 0.f, 0.f};
    float mx0 = -INFINITY, mx1 = -INFINITY, mx2 = -INFINITY, mx3 = -INFINITY;

    __syncthreads();

    for (int tt = 0; tt < CT; tt += 2) {
        // both tiles loaded up front into independent buffers (no rotation)
        const short8 bv0 = sb[tt * 64 + lane];
        const short8 bv1 = sb[(tt + 1) * 64 + lane];

        float16 d0, d1, d2, d3;
        MFMA4_V(d0, d1, d2, d3, bv0, a0, a1, a2, a3, z16);
        RED8(d0, mx0);
        RED8(d1, mx1);
        RED8(d2, mx2);
        RED8(d3, mx3);

        // d-buffer reuse: MFMA writes happen strictly after the max3 reads
        // above (in-order issue, later completion) — safe.
        MFMA4_V(d0, d1, d2, d3, bv1, a0, a1, a2, a3, z16);
        RED8(d0, mx0);
        RED8(d1, mx1);
        RED8(d2, mx2);
        RED8(d3, mx3);
    }

    // lanes l and l+32 hold maxes over disjoint col subsets for the same row
    mx0 = fmaxf(mx0, __shfl_xor(mx0, 32, 64));
    mx1 = fmaxf(mx1, __shfl_xor(mx1, 32, 64));
    mx2 = fmaxf(mx2, __shfl_xor(mx2, 32, 64));
    mx3 = fmaxf(mx3, __shfl_xor(mx3, 32, 64));
    if (lane < 32) {
        uint32* s = smax + batch * NPTS + row0 + lane;
        atomicMax(s,      map_f(mx0));
        atomicMax(s + 32, map_f(mx1));
        atomicMax(s + 64, map_f(mx2));
        atomicMax(s + 96, map_f(mx3));
    }
}

// ---------------------------------------------------------------------------
// deterministic 2-stage final sum: loss = 2 * sum_i (norms[i] - unmap(smax[i]))
// ---------------------------------------------------------------------------
__global__ __launch_bounds__(256)
void final_stage1(const float* __restrict__ norms, const uint32* __restrict__ smax,
                  float* __restrict__ partials)
{
    const int base = blockIdx.x * 1024;
    float s = 0.f;
    for (int k = threadIdx.x; k < 1024; k += 256) {
        const int i = base + k;
        s += norms[i] - unmap_f(smax[i]);
    }
#pragma unroll
    for (int off = 32; off; off >>= 1) s += __shfl_down(s, off, 64);
    __shared__ float ws4[4];
    if ((threadIdx.x & 63) == 0) ws4[threadIdx.x >> 6] = s;
    __syncthreads();
    if (threadIdx.x == 0) partials[blockIdx.x] = (ws4[0] + ws4[1]) + (ws4[2] + ws4[3]);
}

__global__ void final_stage2(const float* __restrict__ partials, float* __restrict__ out)
{
    float s = partials[threadIdx.x] + partials[threadIdx.x + 64];
#pragma unroll
    for (int off = 32; off; off >>= 1) s += __shfl_down(s, off, 64);
    if (threadIdx.x == 0) *out = 2.0f * s;
}

extern "C" void kernel_launch(void* const* d_in, const int* in_sizes, int n_in,
                              void* d_out, int out_size, void* d_ws, size_t ws_size,
                              hipStream_t stream) {
    const float* preds = (const float*)d_in[0];  // [B, M, 3]
    const float* gts   = (const float*)d_in[1];  // [B, N, 3]

    char* w = (char*)d_ws;
    float*  norms = (float*)w;                                   // 512 KiB  [haa|hbb]
    uint32* smax  = (uint32*)(w + 8 * (size_t)NPT_TOT);          // 512 KiB  [smax1|smax2]
    const size_t PITCH = 32 * (size_t)NPT_TOT;                   // 2 MiB per packed array
    unsigned short* AG = (unsigned short*)(w + 16 * (size_t)NPT_TOT);
    unsigned short* BG = (unsigned short*)((char*)AG + PITCH);
    unsigned short* AP = (unsigned short*)((char*)AG + 2 * PITCH);
    unsigned short* BP = (unsigned short*)((char*)AG + 3 * PITCH);
    float* partials = (float*)((char*)AG + 4 * PITCH);

    prepass<<<(2 * NPT_TOT) / 256, 256, 0, stream>>>(gts, preds, norms, smax,
                                                     AG, BG, AP, BP);

    // both directions in one launch: z = dir*8 + batch; 1024-col chunks
    dim3 grid(8, 16, 16);   // 2048 blocks
    chamfer_mfma<<<grid, 256, 0, stream>>>(AG, BP, AP, BG, smax);

    final_stage1<<<128, 256, 0, stream>>>(norms, smax, partials);
    final_stage2<<<1, 64, 0, stream>>>(partials, (float*)d_out);
}